// Round 4
// baseline (310.537 us; speedup 1.0000x reference)
//
#include <hip/hip_runtime.h>
#include <hip/hip_bf16.h>
#include <math.h>
#include <stdint.h>

typedef _Float16 f16;
typedef _Float16 f16x8 __attribute__((ext_vector_type(8)));
typedef float f32x16 __attribute__((ext_vector_type(16)));

#define DIM 256
#define LOSCALE 2048.0f
#define INV_LOSCALE (1.0f/2048.0f)

// B' stream: 4096 codes x 256 depth x {hi,lo}, fragment-major:
// block1KB index b = (col*16 + s)*2 + t   (col 0..127, k-step s 0..15, t 0:hi 1:lo)
// within block: lane l holds 16B = e[code=col*32+(l&31)][depth=s*16+(l>>5)*8 .. +8]
#define BP_BYTES (4096u*1024u + 16384u)   // 4 MB stream + 2 phantom groups pad

// ---------------------------------------------------------------------------
// pack codebook into fragment-major hi/lo f16 stream
// ---------------------------------------------------------------------------
__global__ void vq_pack2(const float* __restrict__ emb, f16* __restrict__ bp)
{
    int o = blockIdx.x * blockDim.x + threadIdx.x;   // one per 16B chunk, 262144
    int l = o & 63;
    int b = o >> 6;
    int t   = b & 1;
    int s   = (b >> 1) & 15;
    int col = b >> 5;
    int code  = col * 32 + (l & 31);
    int depth = s * 16 + (l >> 5) * 8;
    const float* gp = emb + (size_t)code * DIM + depth;
    float4 x0 = *(const float4*)gp;
    float4 x1 = *(const float4*)(gp + 4);
    float xs[8] = {x0.x, x0.y, x0.z, x0.w, x1.x, x1.y, x1.z, x1.w};
    f16x8 v;
    #pragma unroll
    for (int j = 0; j < 8; ++j) {
        f16 h = (f16)xs[j];
        v[j] = t ? (f16)((xs[j] - (float)h) * LOSCALE) : h;
    }
    *(f16x8*)(bp + (size_t)o * 8) = v;
}

// ||e_k||^2, one 64-thread block per code (fp32, full precision)
__global__ void vq_e2(const float* __restrict__ emb, float* __restrict__ e2) {
    int k = blockIdx.x;
    int l = threadIdx.x;
    float4 v = ((const float4*)(emb + (size_t)k * DIM))[l];
    float s = v.x * v.x + v.y * v.y + v.z * v.z + v.w * v.w;
    #pragma unroll
    for (int off = 32; off; off >>= 1) s += __shfl_xor(s, off);
    if (l == 0) e2[k] = s;
}

__global__ void vq_zero(int* __restrict__ p, int n) {
    int i = blockIdx.x * blockDim.x + threadIdx.x;
    if (i < n) p[i] = 0;
}

// ---------------------------------------------------------------------------
// Barrier-free MFMA argmin: 1 wave per 32 rows. A hi/lo in regs,
// B streamed sequentially from L2 (fragment-major), reg double-buffered.
// ---------------------------------------------------------------------------
__global__ __launch_bounds__(64, 1) void vq_argmin3(
    const float* __restrict__ z, const char* __restrict__ bp,
    const float* __restrict__ e2, float* __restrict__ idxf)
{
    const int l    = threadIdx.x;
    const int l31  = l & 31;
    const int hi5  = l >> 5;
    const int rowbase = blockIdx.x * 32;

    // ---- A panel to registers: row = l&31, depth chunk (l>>5)*8 per step ----
    f16x8 a_h[16], a_l[16];
    {
        const float* zr = z + (size_t)(rowbase + l31) * DIM + hi5 * 8;
        #pragma unroll
        for (int s = 0; s < 16; ++s) {
            float4 x0 = *(const float4*)(zr + s * 16);
            float4 x1 = *(const float4*)(zr + s * 16 + 4);
            float xs[8] = {x0.x, x0.y, x0.z, x0.w, x1.x, x1.y, x1.z, x1.w};
            #pragma unroll
            for (int j = 0; j < 8; ++j) {
                f16 h = (f16)xs[j];
                a_h[s][j] = h;
                a_l[s][j] = (f16)((xs[j] - (float)h) * LOSCALE);
            }
        }
    }

    float    bestd[16];
    unsigned bcol[4];
    #pragma unroll
    for (int q = 0; q < 16; ++q) bestd[q] = 3.4e38f;
    #pragma unroll
    for (int i = 0; i < 4; ++i) bcol[i] = 0u;

    const char* bgp = bp + (size_t)l * 16;   // lane slot; groups advance 8KB

#define LOADG(BH, BL, OFF) do {                                    \
    _Pragma("unroll")                                              \
    for (int i_ = 0; i_ < 4; ++i_) {                               \
        BH[i_] = *(const f16x8*)(bgp + (OFF) + i_ * 2048);         \
        BL[i_] = *(const f16x8*)(bgp + (OFF) + i_ * 2048 + 1024);  \
    } } while (0)

#define COMPUTE(BH, BL, G) do {                                                      \
    _Pragma("unroll")                                                                \
    for (int i_ = 0; i_ < 4; ++i_) {                                                 \
        acc0 = __builtin_amdgcn_mfma_f32_32x32x16_f16(a_h[(G)*4+i_], BH[i_], acc0, 0,0,0); \
        acc1 = __builtin_amdgcn_mfma_f32_32x32x16_f16(a_h[(G)*4+i_], BL[i_], acc1, 0,0,0); \
        acc1 = __builtin_amdgcn_mfma_f32_32x32x16_f16(a_l[(G)*4+i_], BH[i_], acc1, 0,0,0); \
    } } while (0)

    f16x8 h0[4], l0[4], h1[4], l1[4];
    size_t off = 0;
    LOADG(h0, l0, off); off += 8192;      // G0
    LOADG(h1, l1, off); off += 8192;      // G1

    for (int col = 0; col < 128; ++col) {
        float e2c = e2[col * 32 + l31];
        f32x16 acc0, acc1;
        #pragma unroll
        for (int q = 0; q < 16; ++q) { acc0[q] = 0.0f; acc1[q] = 0.0f; }

        // 4 groups of 4 k-steps; compute buf, then refill with group+2
        COMPUTE(h0, l0, 0); LOADG(h0, l0, off); off += 8192;
        COMPUTE(h1, l1, 1); LOADG(h1, l1, off); off += 8192;
        COMPUTE(h0, l0, 2); LOADG(h0, l0, off); off += 8192;
        COMPUTE(h1, l1, 3); LOADG(h1, l1, off); off += 8192;
        // (last 2 iterations read 16KB of pad — never consumed)

        #pragma unroll
        for (int q = 0; q < 16; ++q) {
            float dot  = acc0[q] + acc1[q] * INV_LOSCALE;
            float dist = fmaf(-2.0f, dot, e2c);
            bool  lt   = dist < bestd[q];
            bestd[q]   = lt ? dist : bestd[q];
            const unsigned sh = (unsigned)((q & 3) * 8);
            unsigned nv = (bcol[q >> 2] & ~(0xFFu << sh)) | ((unsigned)col << sh);
            bcol[q >> 2] = lt ? nv : bcol[q >> 2];
        }
    }
#undef LOADG
#undef COMPUTE

    // ---- reduce across 32 code-lanes (halves stay separate: offsets <=16) ----
    #pragma unroll
    for (int q = 0; q < 16; ++q) {
        float    d = bestd[q];
        unsigned c = ((bcol[q >> 2] >> ((q & 3) * 8)) & 0xFFu) * 32u + (unsigned)l31;
        #pragma unroll
        for (int o2 = 16; o2; o2 >>= 1) {
            float    od = __shfl_xor(d, o2);
            unsigned oc = __shfl_xor(c, o2);
            if (od < d || (od == d && oc < c)) { d = od; c = oc; }
        }
        if (l31 == 0) {
            int row = (q & 3) + 8 * (q >> 2) + 4 * hi5;
            idxf[rowbase + row] = (float)c;
        }
    }
}

// ------------------------- round-1 fallback argmin -------------------------
__global__ __launch_bounds__(256, 2) void vq_argmin_f32(
    const float* __restrict__ z, const float* __restrict__ emb,
    const float* __restrict__ e2, float* __restrict__ idxf, int K)
{
    __shared__ float zs[64 * 36];
    __shared__ float es[128 * 36];
    const int t = threadIdx.x;
    const int tx = t & 15;
    const int ty = t >> 4;
    const int rowbase = blockIdx.x * 64;
    const float* zbase = z + (size_t)rowbase * DIM;
    float best[4]; int bidx[4];
    #pragma unroll
    for (int i = 0; i < 4; ++i) { best[i] = 3.4e38f; bidx[i] = 0; }
    for (int kt = 0; kt < K; kt += 128) {
        float acc[4][8];
        #pragma unroll
        for (int i = 0; i < 4; ++i)
            #pragma unroll
            for (int j = 0; j < 8; ++j) acc[i][j] = 0.0f;
        for (int dc = 0; dc < DIM; dc += 32) {
            { int lr = t >> 2, o = (t & 3) * 8;
              const float* gp = zbase + (size_t)lr * DIM + dc + o;
              *(float4*)&zs[lr*36+o]   = *(const float4*)gp;
              *(float4*)&zs[lr*36+o+4] = *(const float4*)(gp+4); }
            { int lc = t >> 1, o = (t & 1) * 16;
              const float* gp = emb + (size_t)(kt+lc) * DIM + dc + o;
              *(float4*)&es[lc*36+o]    = *(const float4*)gp;
              *(float4*)&es[lc*36+o+4]  = *(const float4*)(gp+4);
              *(float4*)&es[lc*36+o+8]  = *(const float4*)(gp+8);
              *(float4*)&es[lc*36+o+12] = *(const float4*)(gp+12); }
            __syncthreads();
            const float* zp = &zs[(ty*4)*36];
            const float* ep = &es[tx*36];
            #pragma unroll
            for (int d = 0; d < 32; d += 4) {
                float4 zv[4], ev[8];
                #pragma unroll
                for (int i = 0; i < 4; ++i) zv[i] = *(const float4*)&zp[i*36+d];
                #pragma unroll
                for (int j = 0; j < 8; ++j) ev[j] = *(const float4*)&ep[j*16*36+d];
                #pragma unroll
                for (int i = 0; i < 4; ++i)
                    #pragma unroll
                    for (int j = 0; j < 8; ++j) {
                        acc[i][j] += zv[i].x*ev[j].x; acc[i][j] += zv[i].y*ev[j].y;
                        acc[i][j] += zv[i].z*ev[j].z; acc[i][j] += zv[i].w*ev[j].w;
                    }
            }
            __syncthreads();
        }
        #pragma unroll
        for (int j = 0; j < 8; ++j) {
            int c = kt + tx + 16*j;
            float ev2 = e2[c];
            #pragma unroll
            for (int i = 0; i < 4; ++i) {
                float dist = ev2 - 2.0f*acc[i][j];
                if (dist < best[i] || (dist == best[i] && c < bidx[i])) { best[i]=dist; bidx[i]=c; }
            }
        }
    }
    #pragma unroll
    for (int i = 0; i < 4; ++i) {
        float bd = best[i]; int bi = bidx[i];
        #pragma unroll
        for (int off = 8; off; off >>= 1) {
            float od = __shfl_xor(bd, off); int oi = __shfl_xor(bi, off);
            if (od < bd || (od == bd && oi < bi)) { bd = od; bi = oi; }
        }
        if (tx == 0) idxf[rowbase + ty*4 + i] = (float)bi;
    }
}

// ------------------------------ epilogue ops -------------------------------
__global__ void vq_gather(const float* __restrict__ emb,
                          const float* __restrict__ idxf,
                          float* __restrict__ zq, int N)
{
    int n = blockIdx.x * 4 + (threadIdx.x >> 6);
    int l = threadIdx.x & 63;
    if (n >= N) return;
    int idx = (int)idxf[n];
    ((float4*)(zq + (size_t)n * DIM))[l] = ((const float4*)(emb + (size_t)idx * DIM))[l];
}

__global__ void vq_hist(const float* __restrict__ idxf, int* __restrict__ counts, int N) {
    int n = blockIdx.x * blockDim.x + threadIdx.x;
    if (n < N) atomicAdd(&counts[(int)idxf[n]], 1);
}

__global__ void vq_ppl(const int* __restrict__ counts, float invN,
                       float* __restrict__ out, int K)
{
    int t = threadIdx.x;
    float s = 0.0f;
    for (int k = t; k < K; k += 256) {
        float p = (float)counts[k] * invN;
        s += p * logf(p + 1e-10f);
    }
    #pragma unroll
    for (int off = 32; off; off >>= 1) s += __shfl_xor(s, off);
    __shared__ float wsum[4];
    if ((t & 63) == 0) wsum[t >> 6] = s;
    __syncthreads();
    if (t == 0) out[0] = expf(-(wsum[0] + wsum[1] + wsum[2] + wsum[3]));
}

extern "C" void kernel_launch(void* const* d_in, const int* in_sizes, int n_in,
                              void* d_out, int out_size, void* d_ws, size_t ws_size,
                              hipStream_t stream)
{
    const float* z   = (const float*)d_in[0];
    const float* emb = (const float*)d_in[1];
    const int N = in_sizes[0] / DIM;   // 32768
    const int K = in_sizes[1] / DIM;   // 4096

    float* out  = (float*)d_out;
    float* zq   = out;
    float* idxf = out + (size_t)N * DIM;
    float* ppl  = idxf + N;

    const size_t NEED = (size_t)BP_BYTES + 16384 + 16384;

    if (ws_size >= NEED && K == 4096 && (N % 32) == 0) {
        f16*   bpk    = (f16*)d_ws;
        float* e2     = (float*)((char*)d_ws + BP_BYTES);
        int*   counts = (int*)((char*)d_ws + BP_BYTES + 16384);

        vq_pack2<<<1024, 256, 0, stream>>>(emb, bpk);
        vq_e2<<<K, 64, 0, stream>>>(emb, e2);
        vq_zero<<<(K + 255) / 256, 256, 0, stream>>>(counts, K);
        vq_argmin3<<<N / 32, 64, 0, stream>>>(z, (const char*)bpk, e2, idxf);
        vq_gather<<<N / 4, 256, 0, stream>>>(emb, idxf, zq, N);
        vq_hist<<<(N + 255) / 256, 256, 0, stream>>>(idxf, counts, N);
        vq_ppl<<<1, 256, 0, stream>>>(counts, 1.0f / (float)N, ppl, K);
    } else {
        float* e2     = (float*)d_ws;
        int*   counts = (int*)((char*)d_ws + (size_t)K * sizeof(float));
        vq_e2<<<K, 64, 0, stream>>>(emb, e2);
        vq_zero<<<(K + 255) / 256, 256, 0, stream>>>(counts, K);
        vq_argmin_f32<<<N / 64, 256, 0, stream>>>(z, emb, e2, idxf, K);
        vq_gather<<<N / 4, 256, 0, stream>>>(emb, idxf, zq, N);
        vq_hist<<<(N + 255) / 256, 256, 0, stream>>>(idxf, counts, N);
        vq_ppl<<<1, 256, 0, stream>>>(counts, 1.0f / (float)N, ppl, K);
    }
}

// Round 5
// 298.236 us; speedup vs baseline: 1.0412x; 1.0412x over previous
//
#include <hip/hip_runtime.h>
#include <hip/hip_bf16.h>
#include <math.h>
#include <stdint.h>

typedef _Float16 f16;
typedef _Float16 f16x8 __attribute__((ext_vector_type(8)));
typedef float f32x16 __attribute__((ext_vector_type(16)));

#define DIM 256
#define LOSCALE 2048.0f
#define INV_LOSCALE (1.0f/2048.0f)

// B' stream: 4096 codes x 256 depth x {hi,lo}, fragment-major:
// block1KB index b = (col*16 + s)*2 + t   (col 0..127, k-step s 0..15, t 0:hi 1:lo)
// within block: lane l holds 16B = e[code=col*32+(l&31)][depth=s*16+(l>>5)*8 .. +8]
#define BP_BYTES (4096u*1024u + 16384u)   // 4 MB stream + 2 phantom groups pad

// ---------------------------------------------------------------------------
// pack codebook into fragment-major hi/lo f16 stream
// ---------------------------------------------------------------------------
__global__ void vq_pack2(const float* __restrict__ emb, f16* __restrict__ bp)
{
    int o = blockIdx.x * blockDim.x + threadIdx.x;   // one per 16B chunk, 262144
    int l = o & 63;
    int b = o >> 6;
    int t   = b & 1;
    int s   = (b >> 1) & 15;
    int col = b >> 5;
    int code  = col * 32 + (l & 31);
    int depth = s * 16 + (l >> 5) * 8;
    const float* gp = emb + (size_t)code * DIM + depth;
    float4 x0 = *(const float4*)gp;
    float4 x1 = *(const float4*)(gp + 4);
    float xs[8] = {x0.x, x0.y, x0.z, x0.w, x1.x, x1.y, x1.z, x1.w};
    f16x8 v;
    #pragma unroll
    for (int j = 0; j < 8; ++j) {
        f16 h = (f16)xs[j];
        v[j] = t ? (f16)((xs[j] - (float)h) * LOSCALE) : h;
    }
    *(f16x8*)(bp + (size_t)o * 8) = v;
}

// ||e_k||^2, one 64-thread block per code (fp32, full precision)
__global__ void vq_e2(const float* __restrict__ emb, float* __restrict__ e2) {
    int k = blockIdx.x;
    int l = threadIdx.x;
    float4 v = ((const float4*)(emb + (size_t)k * DIM))[l];
    float s = v.x * v.x + v.y * v.y + v.z * v.z + v.w * v.w;
    #pragma unroll
    for (int off = 32; off; off >>= 1) s += __shfl_xor(s, off);
    if (l == 0) e2[k] = s;
}

__global__ void vq_zero(int* __restrict__ p, int n) {
    int i = blockIdx.x * blockDim.x + threadIdx.x;
    if (i < n) p[i] = 0;
}

// ---------------------------------------------------------------------------
// Barrier-free MFMA argmin, 2 waves/block: wave w sweeps codes
// [w*2048,(w+1)*2048) over the block's 32 rows. A hi/lo in regs, B streamed
// sequentially from L2 (fragment-major), reg double-buffered. One final
// __syncthreads to combine the two waves' argmins via LDS.
// ---------------------------------------------------------------------------
__global__ __launch_bounds__(128, 2) void vq_argmin4(
    const float* __restrict__ z, const char* __restrict__ bp,
    const float* __restrict__ e2, float* __restrict__ idxf)
{
    __shared__ unsigned long long red[2][32];

    const int t    = threadIdx.x;
    const int l    = t & 63;
    const int w    = t >> 6;          // 0..1: code-half
    const int l31  = l & 31;
    const int hi5  = l >> 5;
    const int rowbase = blockIdx.x * 32;

    // ---- A panel to registers: row = l&31, depth chunk (l>>5)*8 per step ----
    f16x8 a_h[16], a_l[16];
    {
        const float* zr = z + (size_t)(rowbase + l31) * DIM + hi5 * 8;
        #pragma unroll
        for (int s = 0; s < 16; ++s) {
            float4 x0 = *(const float4*)(zr + s * 16);
            float4 x1 = *(const float4*)(zr + s * 16 + 4);
            float xs[8] = {x0.x, x0.y, x0.z, x0.w, x1.x, x1.y, x1.z, x1.w};
            #pragma unroll
            for (int j = 0; j < 8; ++j) {
                f16 h = (f16)xs[j];
                a_h[s][j] = h;
                a_l[s][j] = (f16)((xs[j] - (float)h) * LOSCALE);
            }
        }
    }

    float    bestd[16];
    unsigned bcol[4];
    #pragma unroll
    for (int q = 0; q < 16; ++q) bestd[q] = 3.4e38f;
    #pragma unroll
    for (int i = 0; i < 4; ++i) bcol[i] = 0u;

    // wave's private 2 MB stream segment (64 cols x 32 KB)
    const char* bgp = bp + (size_t)w * 2097152 + (size_t)l * 16;
    const float* e2w = e2 + w * 2048;

#define LOADG(BH, BL, OFF) do {                                    \
    _Pragma("unroll")                                              \
    for (int i_ = 0; i_ < 4; ++i_) {                               \
        BH[i_] = *(const f16x8*)(bgp + (OFF) + i_ * 2048);         \
        BL[i_] = *(const f16x8*)(bgp + (OFF) + i_ * 2048 + 1024);  \
    } } while (0)

#define COMPUTE(BH, BL, G) do {                                                      \
    _Pragma("unroll")                                                                \
    for (int i_ = 0; i_ < 4; ++i_) {                                                 \
        acc0 = __builtin_amdgcn_mfma_f32_32x32x16_f16(a_h[(G)*4+i_], BH[i_], acc0, 0,0,0); \
        acc1 = __builtin_amdgcn_mfma_f32_32x32x16_f16(a_h[(G)*4+i_], BL[i_], acc1, 0,0,0); \
        acc1 = __builtin_amdgcn_mfma_f32_32x32x16_f16(a_l[(G)*4+i_], BH[i_], acc1, 0,0,0); \
    } } while (0)

    f16x8 h0[4], l0[4], h1[4], l1[4];
    size_t off = 0;
    LOADG(h0, l0, off); off += 8192;      // G0
    LOADG(h1, l1, off); off += 8192;      // G1

    for (int col = 0; col < 64; ++col) {
        float e2c = e2w[col * 32 + l31];
        f32x16 acc0, acc1;
        #pragma unroll
        for (int q = 0; q < 16; ++q) { acc0[q] = 0.0f; acc1[q] = 0.0f; }

        // 4 groups of 4 k-steps; compute buf, then refill with group+2
        COMPUTE(h0, l0, 0); LOADG(h0, l0, off); off += 8192;
        COMPUTE(h1, l1, 1); LOADG(h1, l1, off); off += 8192;
        COMPUTE(h0, l0, 2); LOADG(h0, l0, off); off += 8192;
        COMPUTE(h1, l1, 3); LOADG(h1, l1, off); off += 8192;
        // (last iterations prefetch past segment end: wave0 -> wave1's data,
        //  wave1 -> the 16KB pad. Loaded, never consumed.)

        #pragma unroll
        for (int q = 0; q < 16; ++q) {
            float dot  = acc0[q] + acc1[q] * INV_LOSCALE;
            float dist = fmaf(-2.0f, dot, e2c);
            bool  lt   = dist < bestd[q];
            bestd[q]   = lt ? dist : bestd[q];
            const unsigned sh = (unsigned)((q & 3) * 8);
            unsigned nv = (bcol[q >> 2] & ~(0xFFu << sh)) | ((unsigned)col << sh);
            bcol[q >> 2] = lt ? nv : bcol[q >> 2];
        }
    }
#undef LOADG
#undef COMPUTE

    // ---- per-wave reduce across 32 code-lanes, then cross-wave via LDS ----
    #pragma unroll
    for (int q = 0; q < 16; ++q) {
        float    d = bestd[q];
        unsigned c = (unsigned)(w * 2048) +
                     ((bcol[q >> 2] >> ((q & 3) * 8)) & 0xFFu) * 32u + (unsigned)l31;
        #pragma unroll
        for (int o2 = 16; o2; o2 >>= 1) {
            float    od = __shfl_xor(d, o2);
            unsigned oc = __shfl_xor(c, o2);
            if (od < d || (od == d && oc < c)) { d = od; c = oc; }
        }
        if (l31 == 0) {
            int row = (q & 3) + 8 * (q >> 2) + 4 * hi5;
            unsigned u   = __float_as_uint(d);
            unsigned key = u ^ (unsigned)(((int)u >> 31) | 0x80000000);
            red[w][row] = ((unsigned long long)key << 32) | c;
        }
    }
    __syncthreads();
    if (t < 32) {
        unsigned long long b0 = red[0][t];
        unsigned long long b1 = red[1][t];
        unsigned long long b  = b1 < b0 ? b1 : b0;
        idxf[rowbase + t] = (float)(unsigned)(b & 0xffffffffu);
    }
}

// ------------------------- round-1 fallback argmin -------------------------
__global__ __launch_bounds__(256, 2) void vq_argmin_f32(
    const float* __restrict__ z, const float* __restrict__ emb,
    const float* __restrict__ e2, float* __restrict__ idxf, int K)
{
    __shared__ float zs[64 * 36];
    __shared__ float es[128 * 36];
    const int t = threadIdx.x;
    const int tx = t & 15;
    const int ty = t >> 4;
    const int rowbase = blockIdx.x * 64;
    const float* zbase = z + (size_t)rowbase * DIM;
    float best[4]; int bidx[4];
    #pragma unroll
    for (int i = 0; i < 4; ++i) { best[i] = 3.4e38f; bidx[i] = 0; }
    for (int kt = 0; kt < K; kt += 128) {
        float acc[4][8];
        #pragma unroll
        for (int i = 0; i < 4; ++i)
            #pragma unroll
            for (int j = 0; j < 8; ++j) acc[i][j] = 0.0f;
        for (int dc = 0; dc < DIM; dc += 32) {
            { int lr = t >> 2, o = (t & 3) * 8;
              const float* gp = zbase + (size_t)lr * DIM + dc + o;
              *(float4*)&zs[lr*36+o]   = *(const float4*)gp;
              *(float4*)&zs[lr*36+o+4] = *(const float4*)(gp+4); }
            { int lc = t >> 1, o = (t & 1) * 16;
              const float* gp = emb + (size_t)(kt+lc) * DIM + dc + o;
              *(float4*)&es[lc*36+o]    = *(const float4*)gp;
              *(float4*)&es[lc*36+o+4]  = *(const float4*)(gp+4);
              *(float4*)&es[lc*36+o+8]  = *(const float4*)(gp+8);
              *(float4*)&es[lc*36+o+12] = *(const float4*)(gp+12); }
            __syncthreads();
            const float* zp = &zs[(ty*4)*36];
            const float* ep = &es[tx*36];
            #pragma unroll
            for (int d = 0; d < 32; d += 4) {
                float4 zv[4], ev[8];
                #pragma unroll
                for (int i = 0; i < 4; ++i) zv[i] = *(const float4*)&zp[i*36+d];
                #pragma unroll
                for (int j = 0; j < 8; ++j) ev[j] = *(const float4*)&ep[j*16*36+d];
                #pragma unroll
                for (int i = 0; i < 4; ++i)
                    #pragma unroll
                    for (int j = 0; j < 8; ++j) {
                        acc[i][j] += zv[i].x*ev[j].x; acc[i][j] += zv[i].y*ev[j].y;
                        acc[i][j] += zv[i].z*ev[j].z; acc[i][j] += zv[i].w*ev[j].w;
                    }
            }
            __syncthreads();
        }
        #pragma unroll
        for (int j = 0; j < 8; ++j) {
            int c = kt + tx + 16*j;
            float ev2 = e2[c];
            #pragma unroll
            for (int i = 0; i < 4; ++i) {
                float dist = ev2 - 2.0f*acc[i][j];
                if (dist < best[i] || (dist == best[i] && c < bidx[i])) { best[i]=dist; bidx[i]=c; }
            }
        }
    }
    #pragma unroll
    for (int i = 0; i < 4; ++i) {
        float bd = best[i]; int bi = bidx[i];
        #pragma unroll
        for (int off = 8; off; off >>= 1) {
            float od = __shfl_xor(bd, off); int oi = __shfl_xor(bi, off);
            if (od < bd || (od == bd && oi < bi)) { bd = od; bi = oi; }
        }
        if (tx == 0) idxf[rowbase + ty*4 + i] = (float)bi;
    }
}

// ------------------------------ epilogue ops -------------------------------
__global__ void vq_gather(const float* __restrict__ emb,
                          const float* __restrict__ idxf,
                          float* __restrict__ zq, int N)
{
    int n = blockIdx.x * 4 + (threadIdx.x >> 6);
    int l = threadIdx.x & 63;
    if (n >= N) return;
    int idx = (int)idxf[n];
    ((float4*)(zq + (size_t)n * DIM))[l] = ((const float4*)(emb + (size_t)idx * DIM))[l];
}

__global__ void vq_hist(const float* __restrict__ idxf, int* __restrict__ counts, int N) {
    int n = blockIdx.x * blockDim.x + threadIdx.x;
    if (n < N) atomicAdd(&counts[(int)idxf[n]], 1);
}

__global__ void vq_ppl(const int* __restrict__ counts, float invN,
                       float* __restrict__ out, int K)
{
    int t = threadIdx.x;
    float s = 0.0f;
    for (int k = t; k < K; k += 256) {
        float p = (float)counts[k] * invN;
        s += p * logf(p + 1e-10f);
    }
    #pragma unroll
    for (int off = 32; off; off >>= 1) s += __shfl_xor(s, off);
    __shared__ float wsum[4];
    if ((t & 63) == 0) wsum[t >> 6] = s;
    __syncthreads();
    if (t == 0) out[0] = expf(-(wsum[0] + wsum[1] + wsum[2] + wsum[3]));
}

extern "C" void kernel_launch(void* const* d_in, const int* in_sizes, int n_in,
                              void* d_out, int out_size, void* d_ws, size_t ws_size,
                              hipStream_t stream)
{
    const float* z   = (const float*)d_in[0];
    const float* emb = (const float*)d_in[1];
    const int N = in_sizes[0] / DIM;   // 32768
    const int K = in_sizes[1] / DIM;   // 4096

    float* out  = (float*)d_out;
    float* zq   = out;
    float* idxf = out + (size_t)N * DIM;
    float* ppl  = idxf + N;

    const size_t NEED = (size_t)BP_BYTES + 16384 + 16384;

    if (ws_size >= NEED && K == 4096 && (N % 32) == 0) {
        f16*   bpk    = (f16*)d_ws;
        float* e2     = (float*)((char*)d_ws + BP_BYTES);
        int*   counts = (int*)((char*)d_ws + BP_BYTES + 16384);

        vq_pack2<<<1024, 256, 0, stream>>>(emb, bpk);
        vq_e2<<<K, 64, 0, stream>>>(emb, e2);
        vq_zero<<<(K + 255) / 256, 256, 0, stream>>>(counts, K);
        vq_argmin4<<<N / 32, 128, 0, stream>>>(z, (const char*)bpk, e2, idxf);
        vq_gather<<<N / 4, 256, 0, stream>>>(emb, idxf, zq, N);
        vq_hist<<<(N + 255) / 256, 256, 0, stream>>>(idxf, counts, N);
        vq_ppl<<<1, 256, 0, stream>>>(counts, 1.0f / (float)N, ppl, K);
    } else {
        float* e2     = (float*)d_ws;
        int*   counts = (int*)((char*)d_ws + (size_t)K * sizeof(float));
        vq_e2<<<K, 64, 0, stream>>>(emb, e2);
        vq_zero<<<(K + 255) / 256, 256, 0, stream>>>(counts, K);
        vq_argmin_f32<<<N / 64, 256, 0, stream>>>(z, emb, e2, idxf, K);
        vq_gather<<<N / 4, 256, 0, stream>>>(emb, idxf, zq, N);
        vq_hist<<<(N + 255) / 256, 256, 0, stream>>>(idxf, counts, N);
        vq_ppl<<<1, 256, 0, stream>>>(counts, 1.0f / (float)N, ppl, K);
    }
}

// Round 6
// 241.291 us; speedup vs baseline: 1.2870x; 1.2360x over previous
//
#include <hip/hip_runtime.h>
#include <hip/hip_bf16.h>
#include <math.h>
#include <stdint.h>

typedef _Float16 f16;
typedef _Float16 f16x8 __attribute__((ext_vector_type(8)));
typedef float f32x16 __attribute__((ext_vector_type(16)));

#define DIM 256
#define LOSCALE 2048.0f
#define INV_LOSCALE (1.0f/2048.0f)

// B' stream: 4096 codes x 256 depth x {hi,lo}, fragment-major:
// block1KB index b = (col*16 + s)*2 + t   (col 0..127, k-step s 0..15, t 0:hi 1:lo)
// within block: lane l holds 16B = e[code=col*32+(l&31)][depth=s*16+(l>>5)*8 .. +8]
#define BP_BYTES (4096u*1024u + 16384u)   // 4 MB stream + pad

#define GLOAD16(gp, lp) __builtin_amdgcn_global_load_lds( \
    (const __attribute__((address_space(1))) void*)(gp),  \
    (__attribute__((address_space(3))) void*)(lp), 16, 0, 0)

// ---------------------------------------------------------------------------
// pack codebook into fragment-major hi/lo f16 stream
// ---------------------------------------------------------------------------
__global__ void vq_pack2(const float* __restrict__ emb, f16* __restrict__ bp)
{
    int o = blockIdx.x * blockDim.x + threadIdx.x;   // one per 16B chunk, 262144
    int l = o & 63;
    int b = o >> 6;
    int t   = b & 1;
    int s   = (b >> 1) & 15;
    int col = b >> 5;
    int code  = col * 32 + (l & 31);
    int depth = s * 16 + (l >> 5) * 8;
    const float* gp = emb + (size_t)code * DIM + depth;
    float4 x0 = *(const float4*)gp;
    float4 x1 = *(const float4*)(gp + 4);
    float xs[8] = {x0.x, x0.y, x0.z, x0.w, x1.x, x1.y, x1.z, x1.w};
    f16x8 v;
    #pragma unroll
    for (int j = 0; j < 8; ++j) {
        f16 h = (f16)xs[j];
        v[j] = t ? (f16)((xs[j] - (float)h) * LOSCALE) : h;
    }
    *(f16x8*)(bp + (size_t)o * 8) = v;
}

// ||e_k||^2, one 64-thread block per code (fp32, full precision)
__global__ void vq_e2(const float* __restrict__ emb, float* __restrict__ e2) {
    int k = blockIdx.x;
    int l = threadIdx.x;
    float4 v = ((const float4*)(emb + (size_t)k * DIM))[l];
    float s = v.x * v.x + v.y * v.y + v.z * v.z + v.w * v.w;
    #pragma unroll
    for (int off = 32; off; off >>= 1) s += __shfl_xor(s, off);
    if (l == 0) e2[k] = s;
}

__global__ void vq_zero(int* __restrict__ p, int n) {
    int i = blockIdx.x * blockDim.x + threadIdx.x;
    if (i < n) p[i] = 0;
}

// ---------------------------------------------------------------------------
// MFMA argmin with LDS-shared B stream.
// 512 thr = 8 waves = 4 row-tiles x 2 code-halves; 128 rows/block; grid=N/128.
// A hi/lo in regs per wave. B col (32KB/half) double-buffered in LDS via
// global_load_lds (linear layout), consumed by 4 row-tile waves each.
// 3 independent accumulator chains (acc0, acc1a, acc1b) for MFMA ILP.
// One __syncthreads per col. B traffic: 4 MB per block (4x less than r5).
// ---------------------------------------------------------------------------
__global__ __launch_bounds__(512, 2) void vq_argmin5(
    const float* __restrict__ z, const char* __restrict__ bp,
    const float* __restrict__ e2, float* __restrict__ idxf)
{
    __shared__ __align__(16) char lds[131072];          // 2 x 64KB dbuf
    __shared__ unsigned long long red[2][4][32];        // 2 KB

    const int t    = threadIdx.x;
    const int lane = t & 63;
    const int w    = t >> 6;          // 0..7
    const int rt   = w & 3;           // row-tile
    const int hw   = w >> 2;          // code half
    const int l31  = lane & 31;
    const int hi5  = lane >> 5;
    const int rowbase = blockIdx.x * 128 + rt * 32;

    // ---- A panel to registers: row = l31, depth chunk hi5*8 per k-step ----
    f16x8 a_h[16], a_l[16];
    {
        const float* zr = z + (size_t)(rowbase + l31) * DIM + hi5 * 8;
        #pragma unroll
        for (int s = 0; s < 16; ++s) {
            float4 x0 = *(const float4*)(zr + s * 16);
            float4 x1 = *(const float4*)(zr + s * 16 + 4);
            float xs[8] = {x0.x, x0.y, x0.z, x0.w, x1.x, x1.y, x1.z, x1.w};
            #pragma unroll
            for (int j = 0; j < 8; ++j) {
                f16 h = (f16)xs[j];
                a_h[s][j] = h;
                a_l[s][j] = (f16)((xs[j] - (float)h) * LOSCALE);
            }
        }
    }

    float    bestd[16];
    unsigned bcol[4];
    #pragma unroll
    for (int q = 0; q < 16; ++q) bestd[q] = 3.4e38f;
    #pragma unroll
    for (int i = 0; i < 4; ++i) bcol[i] = 0u;

    // stage local col cc of this wave's half into buffer pb: wave stages its
    // 8KB quarter (rt) of the half's 32KB, as 8 x 1KB (lane x 16B linear).
#define STAGE(pb, cc) do {                                                    \
    const char* src_ = bp + (((size_t)(hw * 64 + (cc))) << 15)                \
                     + (size_t)rt * 8192 + (size_t)lane * 16;                 \
    char* dst_ = lds + (pb) * 65536 + hw * 32768 + rt * 8192;                 \
    _Pragma("unroll")                                                         \
    for (int i_ = 0; i_ < 8; ++i_)                                            \
        GLOAD16(src_ + i_ * 1024, dst_ + i_ * 1024);                          \
    } while (0)

    STAGE(0, 0);
    __syncthreads();
    int cur = 0;

    for (int c = 0; c < 64; ++c) {
        if (c < 63) STAGE(cur ^ 1, c + 1);

        float e2c = e2[hw * 2048 + c * 32 + l31];
        f32x16 acc0, acc1a, acc1b;
        #pragma unroll
        for (int q = 0; q < 16; ++q) { acc0[q] = 0.0f; acc1a[q] = 0.0f; acc1b[q] = 0.0f; }

        const char* bb = lds + cur * 65536 + hw * 32768;
        #pragma unroll
        for (int s = 0; s < 16; ++s) {
            f16x8 bh = *(const f16x8*)(bb + s * 2048 + lane * 16);
            f16x8 bl = *(const f16x8*)(bb + s * 2048 + 1024 + lane * 16);
            acc0  = __builtin_amdgcn_mfma_f32_32x32x16_f16(a_h[s], bh, acc0,  0, 0, 0);
            acc1a = __builtin_amdgcn_mfma_f32_32x32x16_f16(a_h[s], bl, acc1a, 0, 0, 0);
            acc1b = __builtin_amdgcn_mfma_f32_32x32x16_f16(a_l[s], bh, acc1b, 0, 0, 0);
        }

        #pragma unroll
        for (int q = 0; q < 16; ++q) {
            float dot  = fmaf(acc1a[q] + acc1b[q], INV_LOSCALE, acc0[q]);
            float dist = fmaf(-2.0f, dot, e2c);
            bool  lt   = dist < bestd[q];
            bestd[q]   = lt ? dist : bestd[q];
            const unsigned sh = (unsigned)((q & 3) * 8);
            unsigned nv = (bcol[q >> 2] & ~(0xFFu << sh)) | ((unsigned)c << sh);
            bcol[q >> 2] = lt ? nv : bcol[q >> 2];
        }

        __syncthreads();   // staged col visible; buf[cur] free for overwrite
        cur ^= 1;
    }
#undef STAGE

    // ---- per-wave reduce across 32 code-lanes, then cross-half via LDS ----
    #pragma unroll
    for (int q = 0; q < 16; ++q) {
        float    d = bestd[q];
        unsigned c = (unsigned)(hw * 2048) +
                     ((bcol[q >> 2] >> ((q & 3) * 8)) & 0xFFu) * 32u + (unsigned)l31;
        #pragma unroll
        for (int o2 = 16; o2; o2 >>= 1) {
            float    od = __shfl_xor(d, o2);
            unsigned oc = __shfl_xor(c, o2);
            if (od < d || (od == d && oc < c)) { d = od; c = oc; }
        }
        if (l31 == 0) {
            int row = (q & 3) + 8 * (q >> 2) + 4 * hi5;
            unsigned u   = __float_as_uint(d);
            unsigned key = u ^ (unsigned)(((int)u >> 31) | 0x80000000);
            red[hw][rt][row] = ((unsigned long long)key << 32) | c;
        }
    }
    __syncthreads();
    if (t < 128) {
        int rt2 = t >> 5, r = t & 31;
        unsigned long long b0 = red[0][rt2][r];
        unsigned long long b1 = red[1][rt2][r];
        unsigned long long b  = b1 < b0 ? b1 : b0;
        idxf[blockIdx.x * 128 + rt2 * 32 + r] = (float)(unsigned)(b & 0xffffffffu);
    }
}

// ------------------------- round-1 fallback argmin -------------------------
__global__ __launch_bounds__(256, 2) void vq_argmin_f32(
    const float* __restrict__ z, const float* __restrict__ emb,
    const float* __restrict__ e2, float* __restrict__ idxf, int K)
{
    __shared__ float zs[64 * 36];
    __shared__ float es[128 * 36];
    const int t = threadIdx.x;
    const int tx = t & 15;
    const int ty = t >> 4;
    const int rowbase = blockIdx.x * 64;
    const float* zbase = z + (size_t)rowbase * DIM;
    float best[4]; int bidx[4];
    #pragma unroll
    for (int i = 0; i < 4; ++i) { best[i] = 3.4e38f; bidx[i] = 0; }
    for (int kt = 0; kt < K; kt += 128) {
        float acc[4][8];
        #pragma unroll
        for (int i = 0; i < 4; ++i)
            #pragma unroll
            for (int j = 0; j < 8; ++j) acc[i][j] = 0.0f;
        for (int dc = 0; dc < DIM; dc += 32) {
            { int lr = t >> 2, o = (t & 3) * 8;
              const float* gp = zbase + (size_t)lr * DIM + dc + o;
              *(float4*)&zs[lr*36+o]   = *(const float4*)gp;
              *(float4*)&zs[lr*36+o+4] = *(const float4*)(gp+4); }
            { int lc = t >> 1, o = (t & 1) * 16;
              const float* gp = emb + (size_t)(kt+lc) * DIM + dc + o;
              *(float4*)&es[lc*36+o]    = *(const float4*)gp;
              *(float4*)&es[lc*36+o+4]  = *(const float4*)(gp+4);
              *(float4*)&es[lc*36+o+8]  = *(const float4*)(gp+8);
              *(float4*)&es[lc*36+o+12] = *(const float4*)(gp+12); }
            __syncthreads();
            const float* zp = &zs[(ty*4)*36];
            const float* ep = &es[tx*36];
            #pragma unroll
            for (int d = 0; d < 32; d += 4) {
                float4 zv[4], ev[8];
                #pragma unroll
                for (int i = 0; i < 4; ++i) zv[i] = *(const float4*)&zp[i*36+d];
                #pragma unroll
                for (int j = 0; j < 8; ++j) ev[j] = *(const float4*)&ep[j*16*36+d];
                #pragma unroll
                for (int i = 0; i < 4; ++i)
                    #pragma unroll
                    for (int j = 0; j < 8; ++j) {
                        acc[i][j] += zv[i].x*ev[j].x; acc[i][j] += zv[i].y*ev[j].y;
                        acc[i][j] += zv[i].z*ev[j].z; acc[i][j] += zv[i].w*ev[j].w;
                    }
            }
            __syncthreads();
        }
        #pragma unroll
        for (int j = 0; j < 8; ++j) {
            int c = kt + tx + 16*j;
            float ev2 = e2[c];
            #pragma unroll
            for (int i = 0; i < 4; ++i) {
                float dist = ev2 - 2.0f*acc[i][j];
                if (dist < best[i] || (dist == best[i] && c < bidx[i])) { best[i]=dist; bidx[i]=c; }
            }
        }
    }
    #pragma unroll
    for (int i = 0; i < 4; ++i) {
        float bd = best[i]; int bi = bidx[i];
        #pragma unroll
        for (int off = 8; off; off >>= 1) {
            float od = __shfl_xor(bd, off); int oi = __shfl_xor(bi, off);
            if (od < bd || (od == bd && oi < bi)) { bd = od; bi = oi; }
        }
        if (tx == 0) idxf[rowbase + ty*4 + i] = (float)bi;
    }
}

// ------------------------------ epilogue ops -------------------------------
__global__ void vq_gather(const float* __restrict__ emb,
                          const float* __restrict__ idxf,
                          float* __restrict__ zq, int N)
{
    int n = blockIdx.x * 4 + (threadIdx.x >> 6);
    int l = threadIdx.x & 63;
    if (n >= N) return;
    int idx = (int)idxf[n];
    ((float4*)(zq + (size_t)n * DIM))[l] = ((const float4*)(emb + (size_t)idx * DIM))[l];
}

__global__ void vq_hist(const float* __restrict__ idxf, int* __restrict__ counts, int N) {
    int n = blockIdx.x * blockDim.x + threadIdx.x;
    if (n < N) atomicAdd(&counts[(int)idxf[n]], 1);
}

__global__ void vq_ppl(const int* __restrict__ counts, float invN,
                       float* __restrict__ out, int K)
{
    int t = threadIdx.x;
    float s = 0.0f;
    for (int k = t; k < K; k += 256) {
        float p = (float)counts[k] * invN;
        s += p * logf(p + 1e-10f);
    }
    #pragma unroll
    for (int off = 32; off; off >>= 1) s += __shfl_xor(s, off);
    __shared__ float wsum[4];
    if ((t & 63) == 0) wsum[t >> 6] = s;
    __syncthreads();
    if (t == 0) out[0] = expf(-(wsum[0] + wsum[1] + wsum[2] + wsum[3]));
}

extern "C" void kernel_launch(void* const* d_in, const int* in_sizes, int n_in,
                              void* d_out, int out_size, void* d_ws, size_t ws_size,
                              hipStream_t stream)
{
    const float* z   = (const float*)d_in[0];
    const float* emb = (const float*)d_in[1];
    const int N = in_sizes[0] / DIM;   // 32768
    const int K = in_sizes[1] / DIM;   // 4096

    float* out  = (float*)d_out;
    float* zq   = out;
    float* idxf = out + (size_t)N * DIM;
    float* ppl  = idxf + N;

    const size_t NEED = (size_t)BP_BYTES + 16384 + 16384;

    if (ws_size >= NEED && K == 4096 && (N % 128) == 0) {
        f16*   bpk    = (f16*)d_ws;
        float* e2     = (float*)((char*)d_ws + BP_BYTES);
        int*   counts = (int*)((char*)d_ws + BP_BYTES + 16384);

        vq_pack2<<<1024, 256, 0, stream>>>(emb, bpk);
        vq_e2<<<K, 64, 0, stream>>>(emb, e2);
        vq_zero<<<(K + 255) / 256, 256, 0, stream>>>(counts, K);
        vq_argmin5<<<N / 128, 512, 0, stream>>>(z, (const char*)bpk, e2, idxf);
        vq_gather<<<N / 4, 256, 0, stream>>>(emb, idxf, zq, N);
        vq_hist<<<(N + 255) / 256, 256, 0, stream>>>(idxf, counts, N);
        vq_ppl<<<1, 256, 0, stream>>>(counts, 1.0f / (float)N, ppl, K);
    } else {
        float* e2     = (float*)d_ws;
        int*   counts = (int*)((char*)d_ws + (size_t)K * sizeof(float));
        vq_e2<<<K, 64, 0, stream>>>(emb, e2);
        vq_zero<<<(K + 255) / 256, 256, 0, stream>>>(counts, K);
        vq_argmin_f32<<<N / 64, 256, 0, stream>>>(z, emb, e2, idxf, K);
        vq_gather<<<N / 4, 256, 0, stream>>>(emb, idxf, zq, N);
        vq_hist<<<(N + 255) / 256, 256, 0, stream>>>(idxf, counts, N);
        vq_ppl<<<1, 256, 0, stream>>>(counts, 1.0f / (float)N, ppl, K);
    }
}